// Round 9
// baseline (224.639 us; speedup 1.0000x reference)
//
#include <hip/hip_runtime.h>

// Geometry (fixed by reference)
#define NTOK 197
#define NHEADS 12
#define DIM 768
#define PP 20
#define KK 5
#define STOT 397
#define BB 128
#define NIMG 196
#define NALLTOK (BB * NTOK)      // 25216
#define HSTRIDE (NTOK * STOT)    // 78209

static const long long MASK_ELEMS = (long long)BB * NHEADS * NTOK * STOT; // 120129024

typedef float float4b __attribute__((ext_vector_type(4), aligned(16)));

static __device__ __forceinline__ float dot4(float4b a, float4b b) {
    return a.x * b.x + a.y * b.y + a.z * b.z + a.w * b.w;
}

// mask value for column s given routing window start lo and top-5 bitmask
static __device__ __forceinline__ float maskval(int s, int lo, unsigned bits) {
    unsigned d = (unsigned)(s - lo);          // wraps if s < lo
    float inwv = (float)((bits >> (d / 5u)) & 1u);
    return ((s == 0) | (s >= 201)) ? 1.f : (d < 100u ? inwv : 0.f);
}

// ---------------- Kernel 1: inverse norms of the 40 keys at `layer` -------------
__global__ void knorm_kernel(const float* __restrict__ kc,
                             const float* __restrict__ ki,
                             const int* __restrict__ layer_p,
                             float* __restrict__ invn /*40 floats*/) {
    int layer = *layer_p;
    int kid = blockIdx.x;              // 0..39 ; 0-19 cls, 20-39 img
    const float* base = (kid < PP ? kc : ki) + (size_t)layer * PP * DIM;
    const float* kp = base + (size_t)(kid % PP) * DIM;
    int lane = threadIdx.x;            // 64 threads
    float s = 0.f;
    for (int i = lane; i < DIM; i += 64) { float v = kp[i]; s += v * v; }
    #pragma unroll
    for (int m = 1; m < 64; m <<= 1) s += __shfl_xor(s, m, 64);
    if (lane == 0) invn[kid] = 1.0f / fmaxf(sqrtf(s), 1e-12f);
}

// ---------------- Kernel 2: fused route + write ---------------------------------
// 25216 blocks x 256 threads. Route phase = R8 (proven). Write phase: per-row
// alignment phase p, aligned dwordx4 NT stores + <=5 edge scalars per row.
__global__ __launch_bounds__(256) void fused_kernel(
        const float* __restrict__ x,
        const float* __restrict__ kc,
        const float* __restrict__ ki,
        const int* __restrict__ layer_p,
        const float* __restrict__ invn,
        float* __restrict__ out,
        float* __restrict__ dist_ws /* [25216] */) {
    const int bid = blockIdx.x;          // b*197 + t
    const int tid = threadIdx.x;
    const int l = tid & 63;
    const int w = tid >> 6;              // wave 0..3
    const int b = bid / NTOK;
    const int t = bid - b * NTOK;
    const bool is_cls = (t == 0);
    const int layer = *layer_p;

    const float* __restrict__ kb = (is_cls ? kc : ki) + (size_t)layer * PP * DIM;
    const float* __restrict__ xr = x + (size_t)bid * DIM;

    __shared__ float vals[24];           // 21 used

    // --- x row fragment: dims {4l..4l+3, 256+4l.., 512+4l..} --------------------
    float4b xv0 = *(const float4b*)(xr + 4 * l);
    float4b xv1 = *(const float4b*)(xr + 256 + 4 * l);
    float4b xv2 = *(const float4b*)(xr + 512 + 4 * l);

    // --- 5 keys per wave, full 768-dim partial dots -----------------------------
    float acc[5];
    #pragma unroll
    for (int j = 0; j < 5; ++j) {
        const float* kp = kb + (size_t)(5 * w + j) * DIM;
        float4b k0 = *(const float4b*)(kp + 4 * l);
        float4b k1 = *(const float4b*)(kp + 256 + 4 * l);
        float4b k2 = *(const float4b*)(kp + 512 + 4 * l);
        acc[j] = dot4(xv0, k0) + dot4(xv1, k1) + dot4(xv2, k2);
    }
    #pragma unroll
    for (int m = 1; m < 64; m <<= 1) {
        #pragma unroll
        for (int j = 0; j < 5; ++j) acc[j] += __shfl_xor(acc[j], m, 64);
    }
    if (w == 0) {
        float xsq = dot4(xv0, xv0) + dot4(xv1, xv1) + dot4(xv2, xv2);
        #pragma unroll
        for (int m = 1; m < 64; m <<= 1) xsq += __shfl_xor(xsq, m, 64);
        if (l == 0) vals[PP] = xsq;
    }
    if (l == 0) {
        #pragma unroll
        for (int j = 0; j < 5; ++j) vals[5 * w + j] = acc[j];
    }
    __syncthreads();

    // --- uniform top-5 (per wave, redundant): readlane + monotone-int compare ---
    float dotv = vals[l < 21 ? l : 20];
    float ikl = (l < PP) ? invn[(is_cls ? 0 : PP) + l] : 1.0f;
    float sv = dotv * ikl;               // invx>0 applied later: order-preserving
    int ib = __float_as_int(sv);
    unsigned mu = (ib < 0) ? ~(unsigned)ib : ((unsigned)ib | 0x80000000u);

    unsigned su[PP];
    #pragma unroll
    for (int p = 0; p < PP; ++p) su[p] = (unsigned)__builtin_amdgcn_readlane((int)mu, p);
    float xsqv = __uint_as_float((unsigned)__builtin_amdgcn_readlane(__float_as_int(dotv), PP));

    unsigned bits = 0u;
    float sum5 = 0.f;
    #pragma unroll
    for (int j = 0; j < KK; ++j) {
        unsigned best = 0u; int bidx = 0;
        #pragma unroll
        for (int p = 0; p < PP; ++p) {
            bool ok = !((bits >> p) & 1u) && (su[p] > best);
            best = ok ? su[p] : best;
            bidx = ok ? p : bidx;
        }
        bits |= (1u << bidx);
        unsigned fb = (best & 0x80000000u) ? (best & 0x7FFFFFFFu) : ~best;
        sum5 += __uint_as_float(fb);
    }
    float invx = 1.0f / fmaxf(sqrtf(xsqv), 1e-12f);
    if (tid == 0) dist_ws[bid] = (float)KK - sum5 * invx;

    // --- write phase: aligned vec4 streams, 6 heads per 128-thread group --------
    const int lo = is_cls ? 1 : 101;
    const int group = tid >> 7;          // 0,1
    const int j = tid & 127;             // 0..127

    // 7 distinct column values for cols 4j .. 4j+6 (maskval safe for any s)
    const int c0 = 4 * j;
    float v0 = maskval(c0 + 0, lo, bits);
    float v1 = maskval(c0 + 1, lo, bits);
    float v2 = maskval(c0 + 2, lo, bits);
    float v3 = maskval(c0 + 3, lo, bits);
    float v4 = maskval(c0 + 4, lo, bits);
    float v5 = maskval(c0 + 5, lo, bits);
    float v6 = maskval(c0 + 6, lo, bits);
    float4b F0 = {v0, v1, v2, v3};
    float4b F1 = {v1, v2, v3, v4};
    float4b F2 = {v2, v3, v4, v5};
    float4b F3 = {v3, v4, v5, v6};

    #pragma unroll
    for (int hh = 0; hh < 6; ++hh) {
        const int h = hh * 2 + group;
        const size_t R = ((size_t)(b * NHEADS + h) * NTOK + t) * (size_t)STOT;
        const int p = (int)((0u - (unsigned)R) & 3u);   // leading scalars to 16B
        const int nvec = (STOT - p) >> 2;               // 98 or 99
        float* dst = out + R;
        if (j < nvec) {
            float4b V;
            if (p == 0) V = F0;
            else if (p == 1) V = F1;
            else if (p == 2) V = F2;
            else V = F3;
            __builtin_nontemporal_store(V, (float4b*)(dst + p + 4 * j));
        } else if (j >= 120 && j < 125) {               // 5 edge threads
            int i = j - 120;
            int c = (i < p) ? i : (p + 4 * nvec + (i - p));
            if (c < STOT) {
                float ev = maskval(c, lo, bits);
                __builtin_nontemporal_store(ev, dst + c);
            }
        }
    }
}

// ---------------- Kernel 3: dist reduce over 25216 tokens -----------------------
__global__ __launch_bounds__(256) void reduce_kernel(
        const float* __restrict__ dist_ws,
        float* __restrict__ out) {
    const int tid = threadIdx.x;   // single block, 256 threads
    float sc = 0.f, si = 0.f;
    for (int i = tid; i < NALLTOK; i += 256) {
        unsigned qq = (unsigned)i / 197u;
        unsigned r = (unsigned)i - qq * 197u;
        float v = dist_ws[i];
        if (r == 0) sc += v; else si += v;
    }
    #pragma unroll
    for (int m = 1; m < 64; m <<= 1) {
        sc += __shfl_xor(sc, m, 64);
        si += __shfl_xor(si, m, 64);
    }
    __shared__ float lc[4], li[4];
    int lane = tid & 63, wv = tid >> 6;
    if (lane == 0) { lc[wv] = sc; li[wv] = si; }
    __syncthreads();
    if (tid == 0) {
        float c = lc[0] + lc[1] + lc[2] + lc[3];
        float i = li[0] + li[1] + li[2] + li[3];
        out[MASK_ELEMS] = c / (float)(BB * KK) + i / (float)(BB * NIMG * KK);
    }
}

// ---------------- launcher ------------------------------------------------------
extern "C" void kernel_launch(void* const* d_in, const int* in_sizes, int n_in,
                              void* d_out, int out_size, void* d_ws, size_t ws_size,
                              hipStream_t stream) {
    const float* x  = (const float*)d_in[0];
    const float* kc = (const float*)d_in[1];
    const float* ki = (const float*)d_in[2];
    const int* layer = (const int*)d_in[3];
    float* out = (float*)d_out;

    // ws: [0..64) invnorms, [64..64+25216) per-token dist
    float* invn    = (float*)d_ws;
    float* dist_ws = (float*)d_ws + 64;

    knorm_kernel<<<40, 64, 0, stream>>>(kc, ki, layer, invn);
    fused_kernel<<<NALLTOK, 256, 0, stream>>>(x, kc, ki, layer, invn, out, dist_ws);
    reduce_kernel<<<1, 256, 0, stream>>>(dist_ws, out);
}